// Round 1
// baseline (563.493 us; speedup 1.0000x reference)
//
#include <hip/hip_runtime.h>

typedef unsigned short ushort_t;
typedef __attribute__((ext_vector_type(8))) __bf16 bf16x8;
typedef __attribute__((ext_vector_type(4))) float f32x4;
typedef __attribute__((ext_vector_type(8))) unsigned short u16x8;

#define NB 32
#define TT 12
#define NNODE 1024
#define FF 64
#define OO 64
#define TO 768   // TT*OO

__device__ __forceinline__ unsigned short f2bf(float f) {
    unsigned u = __float_as_uint(f);
    u += 0x7FFFu + ((u >> 16) & 1u);           // round-to-nearest-even
    return (unsigned short)(u >> 16);
}
__device__ __forceinline__ float bf2f(unsigned short h) {
    return __uint_as_float(((unsigned)h) << 16);
}

// async global->LDS, 16B per lane; LDS dest = wave-uniform base + lane*16
__device__ __forceinline__ void gload16(const void* g, void* l) {
    __builtin_amdgcn_global_load_lds(
        (const __attribute__((address_space(1))) unsigned int*)g,
        (__attribute__((address_space(3))) unsigned int*)l, 16, 0, 0);
}

// ---------------------------------------------------------------- lambda init
__global__ void k_init(unsigned* lam) {
    if (threadIdx.x < NB) lam[threadIdx.x] = 0x3F800000u;  // 1.0f (the clamp)
}

// ------------------------------------------------- lambda = max row-sum of A
__global__ __launch_bounds__(256) void k_rowmax(const float* __restrict__ A,
                                                unsigned* __restrict__ lam) {
    const int b = blockIdx.x >> 4;        // 32 b x 16 chunks of 64 rows
    const int chunk = blockIdx.x & 15;
    const int w = threadIdx.x >> 6, lane = threadIdx.x & 63;
    const float* Ab = A + (size_t)b * NNODE * NNODE;
    float mx = 0.0f;
    for (int r = 0; r < 16; ++r) {
        const float* rp = Ab + (size_t)(chunk * 64 + w * 16 + r) * NNODE;
        float s = 0.0f;
#pragma unroll
        for (int j = 0; j < 16; ++j) s += rp[lane + j * 64];
#pragma unroll
        for (int off = 32; off > 0; off >>= 1) s += __shfl_down(s, off, 64);
        if (lane == 0) mx = fmaxf(mx, s);
    }
    if (lane == 0) atomicMax(&lam[b], __float_as_uint(mx));  // positive floats: uint order == float order
}

// -------------------------------------- Lbf[b][n][m] = bf16(2*A/lam - I)
__global__ __launch_bounds__(256) void k_conv(const float* __restrict__ A,
                                              const unsigned* __restrict__ lam,
                                              ushort_t* __restrict__ Lbf) {
    const size_t idx = ((size_t)blockIdx.x * 256 + threadIdx.x) * 8;
    const int b = (int)(idx >> 20);
    const float scl = 2.0f / __uint_as_float(lam[b]);
    const unsigned rem = (unsigned)(idx & 1048575u);
    const int n = rem >> 10;
    const int m0 = rem & 1023;
    const float4 v0 = *(const float4*)(A + idx);
    const float4 v1 = *(const float4*)(A + idx + 4);
    const float vv[8] = {v0.x, v0.y, v0.z, v0.w, v1.x, v1.y, v1.z, v1.w};
    u16x8 r;
#pragma unroll
    for (int i = 0; i < 8; ++i) {
        float f = vv[i] * scl - ((m0 + i) == n ? 1.0f : 0.0f);
        r[i] = f2bf(f);
    }
    *(u16x8*)(Lbf + idx) = r;
}

// ------------------------- Theta [3][64 f][64 o] fp32 -> Tht [3][64 o][64 f] bf16
__global__ void k_theta(const float* __restrict__ Th, ushort_t* __restrict__ Tht) {
    int tid = blockIdx.x * 256 + threadIdx.x;
    if (tid < 3 * 64 * 64) {
        int k = tid >> 12, rem = tid & 4095, o = rem >> 6, f = rem & 63;
        Tht[tid] = f2bf(Th[(k << 12) + (f << 6) + o]);
    }
}

// ----------------- feature transform: Rk = x@Theta_k (MFMA, bf16 in / fp32 acc)
// writes: Pb[b,t,n,o]    = bf16(R0 - R2)           (row-major)
//         Zc[b,t*64+o,n] = bf16(R1)                (column-major, k=n contiguous)
//         R2c[b,t*64+o,n]= bf16(R2)
__global__ __launch_bounds__(256) void k_feature(const float* __restrict__ x,
                                                 const ushort_t* __restrict__ Tht,
                                                 ushort_t* __restrict__ Pb,
                                                 ushort_t* __restrict__ Zc,
                                                 ushort_t* __restrict__ R2c) {
    __shared__ ushort_t xt[128 * 64];     // x tile, bf16, [n_loc][f]
    __shared__ ushort_t tb[64 * 136];     // transpose buffer [o][n_loc], padded stride
    const int n0 = blockIdx.x * 128;
    const int t = blockIdx.y;
    const int b = blockIdx.z;
    const int tid = threadIdx.x;
    const int w = tid >> 6, lane = tid & 63, quad = lane >> 4, l15 = lane & 15;

    // stage x tile fp32->bf16
    const float* xb = x + (((size_t)b * TT + t) * NNODE + n0) * FF;
#pragma unroll
    for (int i = 0; i < 8; ++i) {
        int q = i * 256 + tid;
        int row = q >> 4, fq = q & 15;
        const float4 v = *(const float4*)(xb + row * 64 + fq * 4);
        uint2 pk;
        pk.x = (unsigned)f2bf(v.x) | ((unsigned)f2bf(v.y) << 16);
        pk.y = (unsigned)f2bf(v.z) | ((unsigned)f2bf(v.w) << 16);
        *(uint2*)(xt + row * 64 + fq * 4) = pk;
    }
    __syncthreads();

    // A-frags: row = n_loc, k = f
    bf16x8 af[2][2];
#pragma unroll
    for (int rb = 0; rb < 2; ++rb)
#pragma unroll
        for (int ks = 0; ks < 2; ++ks)
            af[rb][ks] = *(const bf16x8*)(xt + (w * 32 + rb * 16 + l15) * 64 + ks * 32 + quad * 8);

    f32x4 acc[3][2][4];
#pragma unroll
    for (int k = 0; k < 3; ++k)
#pragma unroll
        for (int rb = 0; rb < 2; ++rb)
#pragma unroll
            for (int cb = 0; cb < 4; ++cb)
                acc[k][rb][cb] = (f32x4){0.f, 0.f, 0.f, 0.f};

#pragma unroll
    for (int k = 0; k < 3; ++k)
#pragma unroll
        for (int ks = 0; ks < 2; ++ks)
#pragma unroll
            for (int cb = 0; cb < 4; ++cb) {
                // B-frag direct from global (tiny, L1-cached): B[k=f][col=o] from Tht[k][o][f]
                bf16x8 bfr = *(const bf16x8*)(Tht + ((size_t)(k * 64 + cb * 16 + l15)) * 64 + ks * 32 + quad * 8);
#pragma unroll
                for (int rb = 0; rb < 2; ++rb)
                    acc[k][rb][cb] = __builtin_amdgcn_mfma_f32_16x16x32_bf16(af[rb][ks], bfr, acc[k][rb][cb], 0, 0, 0);
            }

    // P = R0 - R2, row-major [b,t,n,o]
    ushort_t* Pbb = Pb + (((size_t)b * TT + t) * NNODE + n0) * OO;
#pragma unroll
    for (int rb = 0; rb < 2; ++rb)
#pragma unroll
        for (int cb = 0; cb < 4; ++cb)
#pragma unroll
            for (int r = 0; r < 4; ++r) {
                int n = w * 32 + rb * 16 + quad * 4 + r;
                int o = cb * 16 + l15;
                Pbb[(size_t)n * OO + o] = f2bf(acc[0][rb][cb][r] - acc[2][rb][cb][r]);
            }

    // R1 -> Zc, R2 -> R2c, transposed via LDS (coalesced 16B global stores)
    for (int pass = 0; pass < 2; ++pass) {
        const int kk = pass ? 2 : 1;
        ushort_t* dst = pass ? R2c : Zc;
#pragma unroll
        for (int rb = 0; rb < 2; ++rb)
#pragma unroll
            for (int cb = 0; cb < 4; ++cb)
#pragma unroll
                for (int r = 0; r < 4; ++r) {
                    int nl = w * 32 + rb * 16 + quad * 4 + r;
                    int o = cb * 16 + l15;
                    tb[o * 136 + nl] = f2bf(acc[kk][rb][cb][r]);
                }
        __syncthreads();
        {
            int o = tid >> 2, seg = tid & 3;
            ushort_t* drow = dst + ((size_t)b * TO + t * 64 + o) * NNODE + n0 + seg * 32;
            const ushort_t* srow = tb + o * 136 + seg * 32;
#pragma unroll
            for (int i = 0; i < 4; ++i)
                *(u16x8*)(drow + i * 8) = *(const u16x8*)(srow + i * 8);
        }
        __syncthreads();
    }
}

// ------------------------------------------------------------- batched GEMM
// D[r][c] = sum_k Aop[b][m0+r][k] * Bop[b][n0+c][k]   (both operands k-contiguous)
// MODE 1: Zc[b][m0+r][n0+c] += 2*D   (Zc preloaded with R1)     [GEMM1: A=R2c, B=L]
// MODE 2: out[b,t,n,o] = relu(P + D), r=n, c=t*64+o             [GEMM2: A=L, B=Zc]
template <int MODE>
__global__ __launch_bounds__(256) void k_gemm(const ushort_t* __restrict__ Aop, size_t aBS,
                                              const ushort_t* __restrict__ Bop, size_t bBS,
                                              ushort_t* __restrict__ Zp,
                                              const ushort_t* __restrict__ Pbp,
                                              float* __restrict__ outp) {
    __shared__ ushort_t At[128 * 32];
    __shared__ ushort_t Bt[128 * 32];
    const int b = blockIdx.z;
    const int m0 = blockIdx.x * 128, n0 = blockIdx.y * 128;
    const int tid = threadIdx.x;
    const int w = tid >> 6, lane = tid & 63, quad = lane >> 4, l15 = lane & 15;
    const int wr = w >> 1, wc = w & 1;
    const ushort_t* Ab = Aop + (size_t)b * aBS + (size_t)m0 * NNODE;
    const ushort_t* Bb = Bop + (size_t)b * bBS + (size_t)n0 * NNODE;

    f32x4 acc[4][4];
#pragma unroll
    for (int i = 0; i < 4; ++i)
#pragma unroll
        for (int j = 0; j < 4; ++j) acc[i][j] = (f32x4){0.f, 0.f, 0.f, 0.f};

    for (int kk = 0; kk < 32; ++kk) {
        const int k0 = kk << 5;
#pragma unroll
        for (int c = 0; c < 2; ++c) {
            const int qb = c * 256 + w * 64;
            const int q = qb + lane;
            const int row = q >> 2, c4 = q & 3;
            gload16(Ab + (size_t)row * NNODE + k0 + c4 * 8, (void*)(At + qb * 8));
            gload16(Bb + (size_t)row * NNODE + k0 + c4 * 8, (void*)(Bt + qb * 8));
        }
        __syncthreads();
        bf16x8 af[4], bf[4];
#pragma unroll
        for (int i = 0; i < 4; ++i) {
            af[i] = *(const bf16x8*)(At + (wr * 64 + i * 16 + l15) * 32 + quad * 8);
            bf[i] = *(const bf16x8*)(Bt + (wc * 64 + i * 16 + l15) * 32 + quad * 8);
        }
#pragma unroll
        for (int i = 0; i < 4; ++i)
#pragma unroll
            for (int j = 0; j < 4; ++j)
                acc[i][j] = __builtin_amdgcn_mfma_f32_16x16x32_bf16(af[i], bf[j], acc[i][j], 0, 0, 0);
        __syncthreads();
    }

    if (MODE == 1) {
        ushort_t* Z = Zp + (size_t)b * TO * NNODE;
#pragma unroll
        for (int i = 0; i < 4; ++i)
#pragma unroll
            for (int r = 0; r < 4; ++r) {
                const int c = m0 + wr * 64 + i * 16 + quad * 4 + r;
#pragma unroll
                for (int j = 0; j < 4; ++j) {
                    const int n = n0 + wc * 64 + j * 16 + l15;
                    ushort_t* p = Z + (size_t)c * NNODE + n;
                    *p = f2bf(bf2f(*p) + 2.0f * acc[i][j][r]);
                }
            }
    } else {
#pragma unroll
        for (int i = 0; i < 4; ++i)
#pragma unroll
            for (int r = 0; r < 4; ++r) {
                const int n = m0 + wr * 64 + i * 16 + quad * 4 + r;
#pragma unroll
                for (int j = 0; j < 4; ++j) {
                    const int c = n0 + wc * 64 + j * 16 + l15;
                    const int t = c >> 6, o = c & 63;
                    const size_t id = (((size_t)b * TT + t) * NNODE + n) * OO + o;
                    outp[id] = fmaxf(bf2f(Pbp[id]) + acc[i][j][r], 0.0f);
                }
            }
    }
}

extern "C" void kernel_launch(void* const* d_in, const int* in_sizes, int n_in,
                              void* d_out, int out_size, void* d_ws, size_t ws_size,
                              hipStream_t stream) {
    const float* x = (const float*)d_in[0];   // [32,12,1024,64]
    const float* A = (const float*)d_in[1];   // [32,1024,1024]
    const float* Th = (const float*)d_in[2];  // [3,64,64]
    float* out = (float*)d_out;               // [32,12,1024,64]
    char* ws = (char*)d_ws;

    // workspace layout (~218 MiB)
    unsigned* lam = (unsigned*)ws;                                       // 128 B
    ushort_t* Lbf = (ushort_t*)(ws + 256);                               // 64 MiB
    ushort_t* R2c = Lbf + (size_t)NB * NNODE * NNODE;                    // 48 MiB
    ushort_t* Zc = R2c + (size_t)NB * TO * NNODE;                        // 48 MiB
    ushort_t* Pb = Zc + (size_t)NB * TO * NNODE;                         // 48 MiB
    ushort_t* Tht = Pb + (size_t)NB * TT * NNODE * OO;                   // 24 KiB

    k_init<<<1, 64, 0, stream>>>(lam);
    k_rowmax<<<512, 256, 0, stream>>>(A, lam);
    k_conv<<<16384, 256, 0, stream>>>(A, lam, Lbf);
    k_theta<<<48, 256, 0, stream>>>(Th, Tht);
    k_feature<<<dim3(8, 12, 32), 256, 0, stream>>>(x, Tht, Pb, Zc, R2c);
    k_gemm<1><<<dim3(6, 8, 32), 256, 0, stream>>>(R2c, (size_t)TO * NNODE,
                                                  Lbf, (size_t)NNODE * NNODE, Zc, nullptr, nullptr);
    k_gemm<2><<<dim3(8, 6, 32), 256, 0, stream>>>(Lbf, (size_t)NNODE * NNODE,
                                                  Zc, (size_t)TO * NNODE, nullptr, Pb, out);
}